// Round 1
// baseline (275.058 us; speedup 1.0000x reference)
//
#include <hip/hip_runtime.h>
#include <math.h>

#define NB 8
#define NS 512
#define NE 32
#define D_ENT 256
#define D_HID 512
#define D_ATT 200

// Kernel A: h_att[b][a] = (mean_s cxt[b,s,:]) @ Wh[:,a]
__global__ __launch_bounds__(256) void hatt_kernel(const float* __restrict__ cxt,
                                                   const float* __restrict__ Wh,
                                                   float* __restrict__ hatt) {
    const int b = blockIdx.x;
    const int t = threadIdx.x;
    __shared__ float cmean[D_HID];
    const float* base = cxt + (size_t)b * NS * D_HID;
    float s0 = 0.f, s1 = 0.f;
    for (int s = 0; s < NS; ++s) {
        s0 += base[s * D_HID + t];
        s1 += base[s * D_HID + t + 256];
    }
    cmean[t]       = s0 * (1.f / NS);
    cmean[t + 256] = s1 * (1.f / NS);
    __syncthreads();
    if (t < D_ATT) {
        float acc = 0.f;
        for (int h = 0; h < D_HID; ++h)
            acc = fmaf(cmean[h], Wh[h * D_ATT + t], acc);
        hatt[b * D_ATT + t] = acc;
    }
}

// Kernel B: per (b,s): e_att = ent_tile @ We; logits = tanh(h+e_att)@Ws;
// softmax over entities; out = weighted sum of ent rows.
__global__ __launch_bounds__(256) void entatt_kernel(const float* __restrict__ ent,
                                                     const float* __restrict__ We,
                                                     const float* __restrict__ Ws,
                                                     const float* __restrict__ hatt,
                                                     float* __restrict__ out) {
    const int bs = blockIdx.x;           // b*NS + s
    const int b  = bs >> 9;              // NS = 512
    const int t  = threadIdx.x;
    const int ta = t & 63;               // lane
    const int te = t >> 6;               // wave id (0..3), owns e in [te*8, te*8+8)

    __shared__ float ent_lds[NE * D_ENT];   // 32 KB
    __shared__ float hatt_lds[D_ATT];
    __shared__ float ws_lds[D_ATT];
    __shared__ float logits_lds[NE];

    // ---- stage ent tile (coalesced float4) + small vectors ----
    const float4* src = reinterpret_cast<const float4*>(ent + (size_t)bs * NE * D_ENT);
    float4* dst = reinterpret_cast<float4*>(ent_lds);
    #pragma unroll
    for (int k = 0; k < 8; ++k) dst[t + k * 256] = src[t + k * 256];
    if (t < D_ATT) {
        hatt_lds[t] = hatt[b * D_ATT + t];
        ws_lds[t]   = Ws[t];
    }
    __syncthreads();

    // ---- phase 1: acc[i][j] = e_att[e = te*8+i][a = ta+64*j] ----
    float acc[8][4];
    #pragma unroll
    for (int i = 0; i < 8; ++i)
        #pragma unroll
        for (int j = 0; j < 4; ++j) acc[i][j] = 0.f;

    int aj[4];
    #pragma unroll
    for (int j = 0; j < 4; ++j) {
        int a = ta + 64 * j;
        aj[j] = (a < D_ATT) ? a : (D_ATT - 1);  // clamp: garbage acc unused later
    }

    const float4* el4 = reinterpret_cast<const float4*>(ent_lds);
    for (int d4 = 0; d4 < D_ENT / 4; ++d4) {
        float4 ev[8];
        #pragma unroll
        for (int i = 0; i < 8; ++i) ev[i] = el4[(te * 8 + i) * (D_ENT / 4) + d4];
        #pragma unroll
        for (int k = 0; k < 4; ++k) {
            const float* wrow = We + (d4 * 4 + k) * D_ATT;
            float wj[4];
            #pragma unroll
            for (int j = 0; j < 4; ++j) wj[j] = wrow[aj[j]];
            #pragma unroll
            for (int i = 0; i < 8; ++i) {
                float e = (k == 0) ? ev[i].x : (k == 1) ? ev[i].y : (k == 2) ? ev[i].z : ev[i].w;
                #pragma unroll
                for (int j = 0; j < 4; ++j) acc[i][j] = fmaf(e, wj[j], acc[i][j]);
            }
        }
    }

    // ---- phase 2: logits[e] = sum_a tanh(hatt[a] + e_att[e][a]) * Ws[a] ----
    float part[8];
    #pragma unroll
    for (int i = 0; i < 8; ++i) part[i] = 0.f;
    #pragma unroll
    for (int j = 0; j < 4; ++j) {
        int a = ta + 64 * j;
        if (a < D_ATT) {
            float ha = hatt_lds[a], wsa = ws_lds[a];
            #pragma unroll
            for (int i = 0; i < 8; ++i)
                part[i] = fmaf(tanhf(ha + acc[i][j]), wsa, part[i]);
        }
    }
    #pragma unroll
    for (int i = 0; i < 8; ++i) {
        float v = part[i];
        v += __shfl_xor(v, 1);
        v += __shfl_xor(v, 2);
        v += __shfl_xor(v, 4);
        v += __shfl_xor(v, 8);
        v += __shfl_xor(v, 16);
        v += __shfl_xor(v, 32);
        part[i] = v;
    }
    if (ta == 0) {
        #pragma unroll
        for (int i = 0; i < 8; ++i) logits_lds[te * 8 + i] = part[i];
    }
    __syncthreads();

    // ---- phase 3: softmax over E (redundant per thread) + weighted sum ----
    float mx = logits_lds[0];
    #pragma unroll
    for (int e = 1; e < NE; ++e) mx = fmaxf(mx, logits_lds[e]);
    float wsum = 0.f, o = 0.f;
    #pragma unroll
    for (int e = 0; e < NE; ++e) {
        float w = __expf(logits_lds[e] - mx);
        wsum += w;
        o = fmaf(w, ent_lds[e * D_ENT + t], o);
    }
    out[(size_t)bs * D_ENT + t] = o / wsum;
}

extern "C" void kernel_launch(void* const* d_in, const int* in_sizes, int n_in,
                              void* d_out, int out_size, void* d_ws, size_t ws_size,
                              hipStream_t stream) {
    const float* cxt = (const float*)d_in[0];
    const float* ent = (const float*)d_in[1];
    const float* We  = (const float*)d_in[2];
    const float* Wh  = (const float*)d_in[3];
    const float* Ws  = (const float*)d_in[4];
    float* out  = (float*)d_out;
    float* hatt = (float*)d_ws;   // NB*D_ATT floats = 6.4 KB

    hipLaunchKernelGGL(hatt_kernel, dim3(NB), dim3(256), 0, stream, cxt, Wh, hatt);
    hipLaunchKernelGGL(entatt_kernel, dim3(NB * NS), dim3(256), 0, stream,
                       ent, We, Ws, hatt, out);
}

// Round 2
// 98.842 us; speedup vs baseline: 2.7828x; 2.7828x over previous
//
#include <hip/hip_runtime.h>
#include <math.h>

#define NB 8
#define NS 512
#define NE 32
#define DE 256
#define DH 512
#define DA 200
#define DAP 224   // padded att dim (7 tiles of 32)
#define NJ 7

typedef __bf16 bf16x8 __attribute__((ext_vector_type(8)));
typedef __bf16 bf16x4 __attribute__((ext_vector_type(4)));
typedef float f32x16 __attribute__((ext_vector_type(16)));

__device__ __forceinline__ float tanh_fast(float x) {
    float e = __expf(2.f * x);
    return 1.f - 2.f / (e + 1.f);
}

// ---- stage 1: partial sums of cxt over s-chunks (512 blocks) ----
__global__ __launch_bounds__(256) void cmean_partial(const float* __restrict__ cxt,
                                                     float* __restrict__ psum) {
    const int g = blockIdx.x;       // b*64 + c
    const int b = g >> 6, c = g & 63;
    const int t = threadIdx.x;
    const float* base = cxt + ((size_t)b * NS + c * 8) * DH;
    float s0 = 0.f, s1 = 0.f;
    #pragma unroll
    for (int s = 0; s < 8; ++s) {
        s0 += base[s * DH + t];
        s1 += base[s * DH + t + 256];
    }
    psum[(size_t)g * DH + t]       = s0;
    psum[(size_t)g * DH + t + 256] = s1;
}

// ---- stage 2: reduce partials -> cmean; hatt[b][a] = cmean @ Wh ----
__global__ __launch_bounds__(256) void hatt_from_psum(const float* __restrict__ psum,
                                                      const float* __restrict__ Wh,
                                                      float* __restrict__ hattw) {
    const int b = blockIdx.x;
    const int t = threadIdx.x;
    __shared__ float cm[DH];
    float s0 = 0.f, s1 = 0.f;
    for (int c = 0; c < 64; ++c) {
        s0 += psum[((size_t)b * 64 + c) * DH + t];
        s1 += psum[((size_t)b * 64 + c) * DH + t + 256];
    }
    cm[t]       = s0 * (1.f / NS);
    cm[t + 256] = s1 * (1.f / NS);
    __syncthreads();
    if (t < DAP) {
        float acc = 0.f;
        if (t < DA)
            for (int h = 0; h < DH; ++h)
                acc = fmaf(cm[h], Wh[h * DA + t], acc);
        hattw[b * DAP + t] = acc;
    }
}

// ---- stage 3: pack We into bf16 B-fragment layout (zero-padded cols) ----
// frag f = nj*16+kk; lane l, elem e: K = kk*16 + (l>>5)*4 + (e&3) + 8*(e>>2),
//                                    n = nj*32 + (l&31)
__global__ __launch_bounds__(64) void wef_build(const float* __restrict__ We,
                                                __bf16* __restrict__ wef) {
    const int f = blockIdx.x;
    const int l = threadIdx.x;
    const int nj = f >> 4, kk = f & 15;
    const int n = nj * 32 + (l & 31);
    bf16x8 v;
    #pragma unroll
    for (int e = 0; e < 8; ++e) {
        int K = kk * 16 + ((l >> 5) << 2) + (e & 3) + 8 * (e >> 2);
        v[e] = (__bf16)((n < DA) ? We[K * DA + n] : 0.f);
    }
    reinterpret_cast<bf16x8*>(wef)[f * 64 + l] = v;
}

// ---- main: per (b,s): MFMA e_att, fused tanh/Ws logits, softmax, fp32 wsum ----
__global__ __launch_bounds__(256, 2) void entatt_main(const float* __restrict__ ent,
                                                      const __bf16* __restrict__ wef,
                                                      const float* __restrict__ hattw,
                                                      const float* __restrict__ Ws,
                                                      float* __restrict__ out) {
    const int t = threadIdx.x;
    const int lane = t & 63;
    const int wid = t >> 6;
    const int g = blockIdx.x;
    const int b = g >> 7;                 // 4 bs per block, 512 bs per b

    __shared__ __bf16 a_lds[16 * 512];    // 16 KB: A fragments [kk][lane][e]
    __shared__ float hatt_lds[DAP], ws_lds[DAP];
    __shared__ float partials[4][NE];

    if (t < DAP) {
        hatt_lds[t] = hattw[b * DAP + t];
        ws_lds[t]   = (t < DA) ? Ws[t] : 0.f;
    }

    // resident B fragments: wave w owns nj = {2w, 2w+1}
    const int nj0 = 2 * wid, nj1 = 2 * wid + 1;
    const bool has1 = (nj1 < NJ);
    const int nj1c = has1 ? nj1 : nj0;
    bf16x8 B0[16], B1[16];
    const bf16x8* wef8 = reinterpret_cast<const bf16x8*>(wef);
    #pragma unroll
    for (int kk = 0; kk < 16; ++kk) {
        B0[kk] = wef8[(nj0 * 16 + kk) * 64 + lane];
        B1[kk] = wef8[(nj1c * 16 + kk) * 64 + lane];
    }

    for (int i = 0; i < 4; ++i) {
        const int bs = g * 4 + i;
        const float* entb = ent + (size_t)bs * (NE * DE);

        // ---- stage ent tile -> bf16 A-fragment LDS ----
        #pragma unroll
        for (int it = 0; it < 4; ++it) {
            const int m  = t & 31;
            const int k0 = ((t >> 5) * 8) + it * 64;
            const int kk = k0 >> 4;
            const int h8 = (k0 >> 3) & 1;
            const float4 v0 = *reinterpret_cast<const float4*>(&entb[m * DE + k0]);
            const float4 v1 = *reinterpret_cast<const float4*>(&entb[m * DE + k0 + 4]);
            bf16x4 w0 = { (__bf16)v0.x, (__bf16)v0.y, (__bf16)v0.z, (__bf16)v0.w };
            bf16x4 w1 = { (__bf16)v1.x, (__bf16)v1.y, (__bf16)v1.z, (__bf16)v1.w };
            *reinterpret_cast<bf16x4*>(&a_lds[kk * 512 + m * 8 + 4 * h8])        = w0;
            *reinterpret_cast<bf16x4*>(&a_lds[kk * 512 + (m + 32) * 8 + 4 * h8]) = w1;
        }
        __syncthreads();

        // ---- phase 1: MFMA ----
        f32x16 acc0, acc1;
        #pragma unroll
        for (int r = 0; r < 16; ++r) { acc0[r] = 0.f; acc1[r] = 0.f; }
        const bf16x8* ap = reinterpret_cast<const bf16x8*>(a_lds) + lane;
        #pragma unroll
        for (int kk = 0; kk < 16; ++kk) {
            bf16x8 av = ap[kk * 64];
            acc0 = __builtin_amdgcn_mfma_f32_32x32x16_bf16(av, B0[kk], acc0, 0, 0, 0);
            if (has1)
                acc1 = __builtin_amdgcn_mfma_f32_32x32x16_bf16(av, B1[kk], acc1, 0, 0, 0);
        }

        // ---- phase 2: logits = sum_a tanh(hatt + e_att) * Ws ----
        float part[16];
        #pragma unroll
        for (int r = 0; r < 16; ++r) part[r] = 0.f;
        {
            const int a0 = nj0 * 32 + (lane & 31);
            const float ha = hatt_lds[a0], wsa = ws_lds[a0];
            #pragma unroll
            for (int r = 0; r < 16; ++r) part[r] += tanh_fast(acc0[r] + ha) * wsa;
        }
        if (has1) {
            const int a1 = nj1 * 32 + (lane & 31);
            const float ha = hatt_lds[a1], wsa = ws_lds[a1];
            #pragma unroll
            for (int r = 0; r < 16; ++r) part[r] += tanh_fast(acc1[r] + ha) * wsa;
        }
        #pragma unroll
        for (int r = 0; r < 16; ++r) {
            float v = part[r];
            v += __shfl_xor(v, 1);  v += __shfl_xor(v, 2);  v += __shfl_xor(v, 4);
            v += __shfl_xor(v, 8);  v += __shfl_xor(v, 16);
            part[r] = v;
        }
        if ((lane & 31) == 0) {
            const int hi = (lane >> 5) * 4;
            #pragma unroll
            for (int r = 0; r < 16; ++r)
                partials[wid][(r & 3) + 8 * (r >> 2) + hi] = part[r];
        }
        __syncthreads();

        // ---- phase 3: softmax over entities + fp32 weighted sum ----
        float lg[NE];
        float mx = -1e30f;
        #pragma unroll
        for (int e = 0; e < NE; ++e) {
            float v = partials[0][e] + partials[1][e] + partials[2][e] + partials[3][e];
            lg[e] = v;
            mx = fmaxf(mx, v);
        }
        float wsum = 0.f;
        #pragma unroll
        for (int e = 0; e < NE; ++e) { float w = __expf(lg[e] - mx); lg[e] = w; wsum += w; }
        float o = 0.f;
        #pragma unroll
        for (int e = 0; e < NE; ++e) o = fmaf(lg[e], entb[e * DE + t], o);
        out[(size_t)bs * DE + t] = o * (1.f / wsum);
    }
}

extern "C" void kernel_launch(void* const* d_in, const int* in_sizes, int n_in,
                              void* d_out, int out_size, void* d_ws, size_t ws_size,
                              hipStream_t stream) {
    const float* cxt = (const float*)d_in[0];
    const float* ent = (const float*)d_in[1];
    const float* We  = (const float*)d_in[2];
    const float* Wh  = (const float*)d_in[3];
    const float* Ws  = (const float*)d_in[4];
    float* out = (float*)d_out;

    float*  psum  = (float*)d_ws;                       // 512*512 f32 = 1 MB
    float*  hattw = psum + 512 * DH;                    // 8*224 f32
    __bf16* wef   = (__bf16*)(hattw + NB * DAP);        // 7*16*512 bf16 = 112 KB

    hipLaunchKernelGGL(cmean_partial, dim3(512), dim3(256), 0, stream, cxt, psum);
    hipLaunchKernelGGL(hatt_from_psum, dim3(NB), dim3(256), 0, stream, psum, Wh, hattw);
    hipLaunchKernelGGL(wef_build, dim3(NJ * 16), dim3(64), 0, stream, We, wef);
    hipLaunchKernelGGL(entatt_main, dim3(1024), dim3(256), 0, stream,
                       ent, wef, hattw, Ws, out);
}